// Round 1
// baseline (130.216 us; speedup 1.0000x reference)
//
#include <hip/hip_runtime.h>

// BSQ: recon = sign(x @ Wp + bp) @ Wr + br   (normalize is sign-invariant)
// x: [65536][512] f32, Wp: [512][16], bp: [16], Wr: [16][512], br: [512]
// One row per wave-PAIR (2 waves, 128 lanes). Lane (h, dg, cg):
//   - projection: c-slice = h*256 + cg*16 .. +15, d-slice = dg*4 .. +3
//   - weights held in registers (Wp slice 64 f32, Wr slice 64 f32)
//   - f64 accumulation (exact signs vs fp32-order ambiguity near z==0)
//   - recon: output slice = 4 consecutive floats per lane (float4 store)

#define THREADS 256
#define BLOCKS 1024
#define PAIRS_TOTAL (BLOCKS * 2)   // 2048
#define ITERS (65536 / PAIRS_TOTAL) // 32

__global__ __launch_bounds__(THREADS, 2)
void bsq_kernel(const float* __restrict__ x,
                const float* __restrict__ Wp,
                const float* __restrict__ bp,
                const float* __restrict__ Wr,
                const float* __restrict__ br,
                float* __restrict__ out)
{
    const int tid  = threadIdx.x;
    const int wave = tid >> 6;     // 0..3
    const int pair = wave >> 1;    // 0..1 within block
    const int h    = wave & 1;     // half of the pair
    const int l    = tid & 63;
    const int cg   = l & 15;       // c-group within wave
    const int dg   = l >> 4;       // d-group: d = dg*4+q
    const int cbase = h * 256 + cg * 16;
    const int ol    = h * 64 + l;  // 0..127: output lane within pair

    const float4* x4  = (const float4*)x;
    const float4* Wp4 = (const float4*)Wp;
    const float4* Wr4 = (const float4*)Wr;
    const float4* br4 = (const float4*)br;
    const float4* bp4 = (const float4*)bp;
    float4* out4 = (float4*)out;

    // ---- stage weights into registers (reused for all 32 rows) ----
    float4 wpv[16];                 // Wp[cbase+j][dg*4 .. +3]
#pragma unroll
    for (int j = 0; j < 16; ++j)
        wpv[j] = Wp4[(cbase + j) * 4 + dg];

    float4 wrv[16];                 // Wr[d][ol*4 .. +3]
#pragma unroll
    for (int d = 0; d < 16; ++d)
        wrv[d] = Wr4[d * 128 + ol];

    const float4 brv = br4[ol];
    const float4 bpv = bp4[dg];
    const double bpd0 = (double)bpv.x, bpd1 = (double)bpv.y,
                 bpd2 = (double)bpv.z, bpd3 = (double)bpv.w;

    __shared__ double zbuf[2][2][2][16];  // [pair][dbuf][h][d]

    const int pg = blockIdx.x * 2 + pair; // 0..2047

    // prefetch row 0's x slice
    float4 xv[4];
    {
        const float4* xr = x4 + (size_t)pg * 128 + h * 64 + cg * 4;
#pragma unroll
        for (int j = 0; j < 4; ++j) xv[j] = xr[j];
    }

    for (int it = 0; it < ITERS; ++it) {
        const int row = it * PAIRS_TOTAL + pg;

        float4 xc[4];
#pragma unroll
        for (int j = 0; j < 4; ++j) xc[j] = xv[j];

        // prefetch next row while computing this one
        if (it + 1 < ITERS) {
            const float4* xr = x4 + (size_t)(row + PAIRS_TOTAL) * 128 + h * 64 + cg * 4;
#pragma unroll
            for (int j = 0; j < 4; ++j) xv[j] = xr[j];
        }

        // ---- projection: exact-in-f64 partial dot over 16 local c ----
        double a0 = 0.0, a1 = 0.0, a2 = 0.0, a3 = 0.0;
#pragma unroll
        for (int j = 0; j < 4; ++j) {
            const float4 xj = xc[j];
            const float xe[4] = { xj.x, xj.y, xj.z, xj.w };
#pragma unroll
            for (int e = 0; e < 4; ++e) {
                const double xd = (double)xe[e];
                const float4 w = wpv[j * 4 + e];
                a0 = fma(xd, (double)w.x, a0);
                a1 = fma(xd, (double)w.y, a1);
                a2 = fma(xd, (double)w.z, a2);
                a3 = fma(xd, (double)w.w, a3);
            }
        }

        // ---- butterfly reduce over the 16 cg lanes (offsets 1,2,4,8) ----
#pragma unroll
        for (int off = 1; off < 16; off <<= 1) {
            a0 += __shfl_xor(a0, off, 64);
            a1 += __shfl_xor(a1, off, 64);
            a2 += __shfl_xor(a2, off, 64);
            a3 += __shfl_xor(a3, off, 64);
        }

        // ---- cross-wave (pair) combine via tiny LDS exchange ----
        const int db = it & 1;
        if (cg == 0) {
            zbuf[pair][db][h][dg * 4 + 0] = a0;
            zbuf[pair][db][h][dg * 4 + 1] = a1;
            zbuf[pair][db][h][dg * 4 + 2] = a2;
            zbuf[pair][db][h][dg * 4 + 3] = a3;
        }
        __syncthreads();
        const double* zo = &zbuf[pair][db][h ^ 1][dg * 4];
        const double z0 = a0 + zo[0] + bpd0;
        const double z1 = a1 + zo[1] + bpd1;
        const double z2 = a2 + zo[2] + bpd2;
        const double z3 = a3 + zo[3] + bpd3;

        // ---- pack sign bits, broadcast full 16-bit mask to all lanes ----
        int m = ((z0 >= 0.0 ? 1 : 0) |
                 (z1 >= 0.0 ? 2 : 0) |
                 (z2 >= 0.0 ? 4 : 0) |
                 (z3 >= 0.0 ? 8 : 0)) << (dg * 4);
        m |= __shfl_xor(m, 16, 64);
        m |= __shfl_xor(m, 32, 64);

        // ---- recon: out[4] = br + sum_d (+-1)*Wr[d][...] ----
        float4 o = brv;
#pragma unroll
        for (int d = 0; d < 16; ++d) {
            const float s = ((m >> d) & 1) ? 1.0f : -1.0f;
            o.x = fmaf(s, wrv[d].x, o.x);
            o.y = fmaf(s, wrv[d].y, o.y);
            o.z = fmaf(s, wrv[d].z, o.z);
            o.w = fmaf(s, wrv[d].w, o.w);
        }
        out4[(size_t)row * 128 + ol] = o;
    }
}

extern "C" void kernel_launch(void* const* d_in, const int* in_sizes, int n_in,
                              void* d_out, int out_size, void* d_ws, size_t ws_size,
                              hipStream_t stream) {
    const float* x  = (const float*)d_in[0];
    const float* Wp = (const float*)d_in[1];
    const float* bp = (const float*)d_in[2];
    const float* Wr = (const float*)d_in[3];
    const float* br = (const float*)d_in[4];
    float* out = (float*)d_out;

    bsq_kernel<<<BLOCKS, THREADS, 0, stream>>>(x, Wp, bp, Wr, br, out);
}

// Round 2
// 104.578 us; speedup vs baseline: 1.2452x; 1.2452x over previous
//
#include <hip/hip_runtime.h>
#include <stdint.h>

// BSQ split into two kernels via a 128 KB sign-mask in d_ws.
// recon = sign(x @ Wp + bp) @ Wr + br   (L2-normalize is sign-invariant)
// x: [65536][512] f32, Wp: [512][16], bp: [16], Wr: [16][512], br: [512]
//
// Kernel A (sign): block = 256 thr (4 waves), one row per block-iteration.
//   wave w owns c in [w*128, w*128+128); lane (cg = l>>4, dg = l&15) owns
//   32 contiguous c for ONE d => Wp slice = 32 VGPR, butterfly = 2 shuffles.
//   Dot in f32; if any |z_d| < TAU (block-uniform, ~2% of rows) redo the
//   row in exact f64 from the same registers (signs must match the f64-exact
//   reference: round-1 measured absmax 0.0 with full-f64).
// Kernel B (recon): block = 128 thr (pair), Wr slice in 64 VGPR,
//   mask via uniform load, pure streaming-write of 67 MB.

#define ROWS    65536
#define ABLOCKS 2048
#define AITER   (ROWS / ABLOCKS)   // 32
#define TAU     1e-3f

#define BBLOCKS 2048
#define BITER   (ROWS / BBLOCKS)   // 32

__global__ __launch_bounds__(256, 4)
void sign_kernel(const float* __restrict__ x,
                 const float* __restrict__ Wp,
                 const float* __restrict__ bp,
                 uint16_t* __restrict__ mask)
{
    const int tid = threadIdx.x;
    const int w   = tid >> 6;      // wave 0..3: c-quarter
    const int l   = tid & 63;
    const int cg  = l >> 4;        // 0..3  : c-subgroup within wave
    const int dg  = l & 15;        // 0..15 : this lane's d
    const int cbase = w * 128 + cg * 32;   // lane's 32-c slice start

    // Wp slice: Wp[cbase+k][dg], k=0..31 (scattered, L2-hot, once per block)
    float wp[32];
#pragma unroll
    for (int k = 0; k < 32; ++k)
        wp[k] = Wp[(cbase + k) * 16 + dg];

    const float  bpf = bp[dg];
    const double bpd = (double)bpf;

    __shared__ float  zb32[2][4][16];   // [dbuf][wave][d]
    __shared__ double zb64[4][16];      // slow path (rare)

    const float4* x4  = (const float4*)x;
    const int     xoff = w * 32 + cg * 8;   // float4 index of lane's slice

    float4 xa[8], xb[8];
    {
        const float4* p = x4 + (size_t)blockIdx.x * 128 + xoff;
#pragma unroll
        for (int j = 0; j < 8; ++j) xa[j] = p[j];
    }

    auto process = [&](int it, float4 (&xc)[8], float4 (&xn)[8]) {
        const int row = it * ABLOCKS + blockIdx.x;

        // prefetch next row while computing this one
        if (it + 1 < AITER) {
            const float4* p = x4 + (size_t)(row + ABLOCKS) * 128 + xoff;
#pragma unroll
            for (int j = 0; j < 8; ++j) xn[j] = p[j];
        }

        // ---- f32 partial dot over this lane's 32 c ----
        float a = 0.0f;
#pragma unroll
        for (int j = 0; j < 8; ++j) {
            a = fmaf(xc[j].x, wp[j * 4 + 0], a);
            a = fmaf(xc[j].y, wp[j * 4 + 1], a);
            a = fmaf(xc[j].z, wp[j * 4 + 2], a);
            a = fmaf(xc[j].w, wp[j * 4 + 3], a);
        }
        // reduce over the 4 cg lanes (l bits 4,5)
        a += __shfl_xor(a, 16, 64);
        a += __shfl_xor(a, 32, 64);

        const int db = it & 1;
        if (cg == 0) zb32[db][w][dg] = a;
        __syncthreads();
        const float z = zb32[db][0][dg] + zb32[db][1][dg]
                      + zb32[db][2][dg] + zb32[db][3][dg] + bpf;

        bool sgn;
        // block-uniform (z identical across waves per dg): safe to branch+barrier
        const unsigned long long amb = __ballot(fabsf(z) < TAU);
        if (amb) {
            // ---- rare exact-f64 redo of the whole row ----
            double ad = 0.0;
#pragma unroll
            for (int j = 0; j < 8; ++j) {
                ad = fma((double)xc[j].x, (double)wp[j * 4 + 0], ad);
                ad = fma((double)xc[j].y, (double)wp[j * 4 + 1], ad);
                ad = fma((double)xc[j].z, (double)wp[j * 4 + 2], ad);
                ad = fma((double)xc[j].w, (double)wp[j * 4 + 3], ad);
            }
            ad += __shfl_xor(ad, 16, 64);
            ad += __shfl_xor(ad, 32, 64);
            if (cg == 0) zb64[w][dg] = ad;
            __syncthreads();
            const double zd = zb64[0][dg] + zb64[1][dg]
                            + zb64[2][dg] + zb64[3][dg] + bpd;
            sgn = (zd >= 0.0);
            // zb64 WAR across iterations is protected by the next iteration's
            // fast-path barrier (reads here precede it in program order).
        } else {
            sgn = (z >= 0.0f);
        }

        const unsigned long long bits = __ballot(sgn);  // bits 0..15 = d 0..15
        if (tid == 0) mask[row] = (uint16_t)(bits & 0xFFFFull);
    };

#pragma unroll 1
    for (int it = 0; it < AITER; it += 2) {
        process(it, xa, xb);
        process(it + 1, xb, xa);
    }
}

__global__ __launch_bounds__(128, 4)
void recon_kernel(const uint16_t* __restrict__ mask,
                  const float* __restrict__ Wr,
                  const float* __restrict__ br,
                  float* __restrict__ out)
{
    const int tid = threadIdx.x;   // 0..127: float4 column of the row
    const float4* Wr4 = (const float4*)Wr;
    const float4* br4 = (const float4*)br;
    float4* out4 = (float4*)out;

    float4 wrv[16];                 // Wr[d][tid*4 .. +3]
#pragma unroll
    for (int d = 0; d < 16; ++d) wrv[d] = Wr4[d * 128 + tid];
    const float4 brv = br4[tid];

    const int pg = blockIdx.x;
    int m = mask[pg];               // uniform (scalar) load, prefetched

#pragma unroll 1
    for (int it = 0; it < BITER; ++it) {
        const int row  = it * BBLOCKS + pg;
        const int mcur = m;
        if (it + 1 < BITER) m = mask[row + BBLOCKS];

        float4 o = brv;
#pragma unroll
        for (int d = 0; d < 16; ++d) {
            const float s = ((mcur >> d) & 1) ? 1.0f : -1.0f;
            o.x = fmaf(s, wrv[d].x, o.x);
            o.y = fmaf(s, wrv[d].y, o.y);
            o.z = fmaf(s, wrv[d].z, o.z);
            o.w = fmaf(s, wrv[d].w, o.w);
        }
        out4[(size_t)row * 128 + tid] = o;
    }
}

extern "C" void kernel_launch(void* const* d_in, const int* in_sizes, int n_in,
                              void* d_out, int out_size, void* d_ws, size_t ws_size,
                              hipStream_t stream) {
    const float* x  = (const float*)d_in[0];
    const float* Wp = (const float*)d_in[1];
    const float* bp = (const float*)d_in[2];
    const float* Wr = (const float*)d_in[3];
    const float* br = (const float*)d_in[4];
    float* out = (float*)d_out;
    uint16_t* mask = (uint16_t*)d_ws;   // 65536 * 2 B = 128 KB

    sign_kernel <<<ABLOCKS, 256, 0, stream>>>(x, Wp, bp, mask);
    recon_kernel<<<BBLOCKS, 128, 0, stream>>>(mask, Wr, br, out);
}

// Round 3
// 98.502 us; speedup vs baseline: 1.3220x; 1.0617x over previous
//
#include <hip/hip_runtime.h>
#include <stdint.h>

// Fused BSQ: recon = sign(x @ Wp + bp) @ Wr + br   (L2-normalize is sign-invariant)
// x: [65536][512] f32, Wp: [512][16], bp: [16], Wr: [16][512], br: [512]
//
// One 4-wave block owns 32 rows (stride-2048 so all blocks stream adjacent rows).
// Per row:
//   sign phase: lane (w, cg=l>>4, dg=l&15) holds Wp[c-slice of 32][dg] in 32 VGPRs;
//     f32 dot -> 2 shuffles -> tiny LDS exchange across the 4 waves.
//     RAW barrier (lgkmcnt(0) only — prefetch loads stay in flight across it;
//     __syncthreads would drain vmcnt and serialize HBM latency per row, the
//     round-2 killer).
//     If any |z_d| < TAU (block-uniform, ~2% of rows): exact-f64 redo from the
//     same registers (reference signs are f64-exact; round 1 measured absmax 0).
//   recon phase: mask is already in every lane via __ballot — no memory round
//     trip. Lane recons one float2 column (Wr slice 32 VGPRs), streaming store.

#define THREADS 256
#define BLOCKS  2048
#define ITERS   (65536 / BLOCKS)   // 32
#define TAU     1e-3f

// barrier that does NOT drain vmcnt: LDS visibility only
#define BAR() asm volatile("s_waitcnt lgkmcnt(0)\n\ts_barrier" ::: "memory")

__global__ __launch_bounds__(THREADS, 3)
void bsq_fused(const float* __restrict__ x,
               const float* __restrict__ Wp,
               const float* __restrict__ bp,
               const float* __restrict__ Wr,
               const float* __restrict__ br,
               float* __restrict__ out)
{
    const int tid = threadIdx.x;
    const int w   = tid >> 6;      // wave 0..3: c-quarter
    const int l   = tid & 63;
    const int cg  = l >> 4;        // c-subgroup within wave
    const int dg  = l & 15;        // this lane's d
    const int cbase = w * 128 + cg * 32;

    // ---- weights in registers (reused for all 32 rows) ----
    float wp[32];                  // Wp[cbase+k][dg]
#pragma unroll
    for (int k = 0; k < 32; ++k)
        wp[k] = Wp[(cbase + k) * 16 + dg];

    float2 wr2[16];                // Wr[d][tid*2 .. +1]
    const float2* Wr2 = (const float2*)Wr;
#pragma unroll
    for (int d = 0; d < 16; ++d)
        wr2[d] = Wr2[d * 256 + tid];
    const float2 br2v = ((const float2*)br)[tid];

    const float  bpf = bp[dg];
    const double bpd = (double)bpf;

    __shared__ __align__(16) float  zb32[2][16][4];  // [dbuf][d][wave]
    __shared__ __align__(16) double zb64[16][4];     // rare exact path

    const float4* x4   = (const float4*)x;
    float2*       out2 = (float2*)out;
    const int     xoff = w * 32 + cg * 8;   // float4 index of lane's c-slice

    float4 xa[8], xb[8];
    {
        const float4* p = x4 + (size_t)blockIdx.x * 128 + xoff;
#pragma unroll
        for (int j = 0; j < 8; ++j) xa[j] = p[j];
    }

    auto process = [&](int it, float4 (&xc)[8], float4 (&xn)[8]) {
        const int row = it * BLOCKS + blockIdx.x;

        // prefetch next row (stays in flight across the raw barrier)
        if (it + 1 < ITERS) {
            const float4* p = x4 + (size_t)(row + BLOCKS) * 128 + xoff;
#pragma unroll
            for (int j = 0; j < 8; ++j) xn[j] = p[j];
        }

        // ---- f32 partial dot over this lane's 32 c (4 chains, 8 deep) ----
        float a0 = 0.f, a1 = 0.f, a2 = 0.f, a3 = 0.f;
#pragma unroll
        for (int j = 0; j < 8; ++j) {
            a0 = fmaf(xc[j].x, wp[4 * j + 0], a0);
            a1 = fmaf(xc[j].y, wp[4 * j + 1], a1);
            a2 = fmaf(xc[j].z, wp[4 * j + 2], a2);
            a3 = fmaf(xc[j].w, wp[4 * j + 3], a3);
        }
        float a = (a0 + a1) + (a2 + a3);
        a += __shfl_xor(a, 16, 64);
        a += __shfl_xor(a, 32, 64);

        const int db = it & 1;
        if (l < 16) zb32[db][dg][w] = a;   // lanes 0..15 carry dg 0..15
        BAR();
        const float4 q = *(const float4*)&zb32[db][dg][0];
        const float  z = (q.x + q.y) + (q.z + q.w) + bpf;

        bool sgn;
        // block-uniform (z depends on dg only, identical in all 4 waves):
        // safe to branch + barrier inside
        const unsigned long long amb = __ballot(fabsf(z) < TAU);
        if (amb) {
            double ad = 0.0;
#pragma unroll
            for (int j = 0; j < 8; ++j) {
                ad = fma((double)xc[j].x, (double)wp[4 * j + 0], ad);
                ad = fma((double)xc[j].y, (double)wp[4 * j + 1], ad);
                ad = fma((double)xc[j].z, (double)wp[4 * j + 2], ad);
                ad = fma((double)xc[j].w, (double)wp[4 * j + 3], ad);
            }
            ad += __shfl_xor(ad, 16, 64);
            ad += __shfl_xor(ad, 32, 64);
            if (l < 16) zb64[dg][w] = ad;
            BAR();
            const double zd = (zb64[dg][0] + zb64[dg][1])
                            + (zb64[dg][2] + zb64[dg][3]) + bpd;
            sgn = (zd >= 0.0);
            // zb64 WAR vs the next ambiguous row is separated by that row's
            // main BAR(); zb32 WAR handled by the double buffer.
        } else {
            sgn = (z >= 0.0f);
        }

        const unsigned long long bits = __ballot(sgn);  // bits 0..15 = d 0..15
        const int m = (int)(bits & 0xFFFFull);          // in EVERY lane

        // ---- recon: lane's float2 column, mask from registers ----
        float ox = br2v.x, oy = br2v.y;
#pragma unroll
        for (int d = 0; d < 16; ++d) {
            const float s = ((m >> d) & 1) ? 1.0f : -1.0f;
            ox = fmaf(s, wr2[d].x, ox);
            oy = fmaf(s, wr2[d].y, oy);
        }
        out2[(size_t)row * 256 + tid] = make_float2(ox, oy);
    };

#pragma unroll 1
    for (int it = 0; it < ITERS; it += 2) {
        process(it, xa, xb);
        process(it + 1, xb, xa);
    }
}

extern "C" void kernel_launch(void* const* d_in, const int* in_sizes, int n_in,
                              void* d_out, int out_size, void* d_ws, size_t ws_size,
                              hipStream_t stream) {
    const float* x  = (const float*)d_in[0];
    const float* Wp = (const float*)d_in[1];
    const float* bp = (const float*)d_in[2];
    const float* Wr = (const float*)d_in[3];
    const float* br = (const float*)d_in[4];
    float* out = (float*)d_out;

    bsq_fused<<<BLOCKS, THREADS, 0, stream>>>(x, Wp, bp, Wr, br, out);
}

// Round 4
// 97.330 us; speedup vs baseline: 1.3379x; 1.0121x over previous
//
#include <hip/hip_runtime.h>
#include <stdint.h>

// Fused BSQ: recon = sign(x @ Wp + bp) @ Wr + br   (L2-normalize is sign-invariant)
// x: [65536][512] f32, Wp: [512][16], bp: [16], Wr: [16][512], br: [512]
//
// Round-4 restructure: kill the per-row sync. Block = 4 waves = one 32-row tile.
//   Phase 1 (no barriers): per row r: f32 dot (lane (w,cg,dg) covers 32 c of one d)
//     -> 2 shuffles -> predicated LDS write zp[r][dg][w]. Rows independent =>
//     shuffle/LDS latency pipelines across rows instead of serializing.
//   ONE barrier.
//   Phase 2 (no barriers): per row: ds_read_b128 of 4 partials + 3 adds + bp
//     -> tau check -> ballot -> mask in every lane -> VALU recon (float2/lane)
//     -> streaming store. Rare (~2%, wave-uniform) f64 exact redo inline with
//     2 barriers (reference signs are f64-exact: rounds 1-3 absmax 0.0).

#define ROWS    65536
#define TILE    32
#define BLOCKS  (ROWS / TILE)      // 2048
#define TAU     1e-3f

// barrier that does NOT drain vmcnt (LDS visibility only)
#define BAR() asm volatile("s_waitcnt lgkmcnt(0)\n\ts_barrier" ::: "memory")

__global__ __launch_bounds__(256, 3)
void bsq_fused(const float* __restrict__ x,
               const float* __restrict__ Wp,
               const float* __restrict__ bp,
               const float* __restrict__ Wr,
               const float* __restrict__ br,
               float* __restrict__ out)
{
    const int tid = threadIdx.x;
    const int w   = tid >> 6;      // wave 0..3: c-quarter
    const int l   = tid & 63;
    const int cg  = l >> 4;        // c-subgroup within wave
    const int dg  = l & 15;        // this lane's d
    const int cbase = w * 128 + cg * 32;

    // ---- weights in registers ----
    float wp[32];                  // Wp[cbase+k][dg]
#pragma unroll
    for (int k = 0; k < 32; ++k)
        wp[k] = Wp[(cbase + k) * 16 + dg];

    float2 wr2[16];                // Wr[d][tid*2 .. +1]
    const float2* Wr2 = (const float2*)Wr;
#pragma unroll
    for (int d = 0; d < 16; ++d)
        wr2[d] = Wr2[d * 256 + tid];
    const float2 br2v = ((const float2*)br)[tid];

    const float  bpf = bp[dg];
    const double bpd = (double)bpf;

    __shared__ __align__(16) float  zp[TILE][16][4];  // [row][d][wave]  8 KB
    __shared__ __align__(16) double zb64[16][4];      // rare exact path

    const float4* x4   = (const float4*)x;
    float2*       out2 = (float2*)out;
    const int     xoff = w * 32 + cg * 8;   // float4 index of lane's c-slice
    const int     row0 = blockIdx.x * TILE;

    // =========================== Phase 1: signs ===========================
    float4 xa[8], xb[8];
    {
        const float4* p = x4 + (size_t)row0 * 128 + xoff;
#pragma unroll
        for (int j = 0; j < 8; ++j) xa[j] = p[j];
    }

    auto sign_row = [&](int r, float4 (&xc)[8], float4 (&xn)[8]) {
        // prefetch next row (no barriers anywhere in this phase)
        if (r + 1 < TILE) {
            const float4* p = x4 + (size_t)(row0 + r + 1) * 128 + xoff;
#pragma unroll
            for (int j = 0; j < 8; ++j) xn[j] = p[j];
        }
        float a0 = 0.f, a1 = 0.f, a2 = 0.f, a3 = 0.f;
#pragma unroll
        for (int j = 0; j < 8; ++j) {
            a0 = fmaf(xc[j].x, wp[4 * j + 0], a0);
            a1 = fmaf(xc[j].y, wp[4 * j + 1], a1);
            a2 = fmaf(xc[j].z, wp[4 * j + 2], a2);
            a3 = fmaf(xc[j].w, wp[4 * j + 3], a3);
        }
        float a = (a0 + a1) + (a2 + a3);
        a += __shfl_xor(a, 16, 64);
        a += __shfl_xor(a, 32, 64);
        if (cg == 0) zp[r][dg][w] = a;     // 16 lanes/wave, 2-way bank alias
    };

#pragma unroll 1
    for (int r = 0; r < TILE; r += 2) {
        sign_row(r,     xa, xb);
        sign_row(r + 1, xb, xa);
    }

    BAR();   // zp visible to all waves; nothing else pending

    // ====================== Phase 2: reduce + recon =======================
#pragma unroll 2
    for (int r = 0; r < TILE; ++r) {
        const int row = row0 + r;

        const float4 q = *reinterpret_cast<const float4*>(&zp[r][dg][0]);
        const float  z = (q.x + q.y) + (q.z + q.w) + bpf;

        bool sgn = (z >= 0.0f);
        // wave-uniform (z depends only on dg; identical in all 4 waves)
        const unsigned long long amb = __ballot(fabsf(z) < TAU);
        if (amb) {
            // ---- rare exact-f64 redo: reload row (L2/L3-hot) ----
            const float4* p = x4 + (size_t)row * 128 + xoff;
            float4 xf[8];
#pragma unroll
            for (int j = 0; j < 8; ++j) xf[j] = p[j];
            double ad = 0.0;
#pragma unroll
            for (int j = 0; j < 8; ++j) {
                ad = fma((double)xf[j].x, (double)wp[4 * j + 0], ad);
                ad = fma((double)xf[j].y, (double)wp[4 * j + 1], ad);
                ad = fma((double)xf[j].z, (double)wp[4 * j + 2], ad);
                ad = fma((double)xf[j].w, (double)wp[4 * j + 3], ad);
            }
            ad += __shfl_xor(ad, 16, 64);
            ad += __shfl_xor(ad, 32, 64);
            if (cg == 0) zb64[dg][w] = ad;
            BAR();
            const double zd = (zb64[dg][0] + zb64[dg][1])
                            + (zb64[dg][2] + zb64[dg][3]) + bpd;
            sgn = (zd >= 0.0);
            BAR();   // all reads done before any future zb64 rewrite
        }

        const unsigned long long bits = __ballot(sgn);  // bits 0..15 = d 0..15
        const int m = (int)(bits & 0xFFFFull);          // in EVERY lane

        float ox = br2v.x, oy = br2v.y;
#pragma unroll
        for (int d = 0; d < 16; ++d) {
            const float s = ((m >> d) & 1) ? 1.0f : -1.0f;
            ox = fmaf(s, wr2[d].x, ox);
            oy = fmaf(s, wr2[d].y, oy);
        }
        out2[(size_t)row * 256 + tid] = make_float2(ox, oy);
    }
}

extern "C" void kernel_launch(void* const* d_in, const int* in_sizes, int n_in,
                              void* d_out, int out_size, void* d_ws, size_t ws_size,
                              hipStream_t stream) {
    const float* x  = (const float*)d_in[0];
    const float* Wp = (const float*)d_in[1];
    const float* bp = (const float*)d_in[2];
    const float* Wr = (const float*)d_in[3];
    const float* br = (const float*)d_in[4];
    float* out = (float*)d_out;

    bsq_fused<<<BLOCKS, 256, 0, stream>>>(x, Wp, bp, Wr, br, out);
}